// Round 5
// baseline (348.345 us; speedup 1.0000x reference)
//
#include <hip/hip_runtime.h>

#define DIMN 1024
#define TN 4096
#define BN 8
#define CBN 4096
#define BTN (BN*TN)
#define OUT_ELEMS (BN*DIMN*TN)

typedef float fx4 __attribute__((ext_vector_type(4)));
typedef float fx2 __attribute__((ext_vector_type(2)));

// ws layout (float offsets)
#define WS_WINT 0          // W_in^T scaled: [d][8], 8192 floats
#define WS_WOUT 8192       // W_out scaled: [o][8], 8192 floats
#define WS_C2   49152      // h = -0.5*sum(c_n^2) per code, 4096 floats
#define WS_CNP  53248      // paired normalized codebook [j/2][8dims][2], 32768 floats
#define WS_LOSS 86016      // 8 floats (per-batch loss accum)
#define WS_CNT  86024      // completion counter (uint bits)
#define WS_ZEEN 131072     // [bt][16]: z_e in [0,8), e_n in [8,16); 524288 floats

__device__ __forceinline__ float dot4(float4 a, float4 b) {
    float d = a.x * b.x;
    d = fmaf(a.y, b.y, d);
    d = fmaf(a.z, b.z, d);
    d = fmaf(a.w, b.w, d);
    return d;
}
__device__ __forceinline__ void add4(float4& a, float4 b) {
    a.x += b.x; a.y += b.y; a.z += b.z; a.w += b.w;
}
__device__ __forceinline__ fx2 lo2(fx4 v) { return __builtin_shufflevector(v, v, 0, 1); }
__device__ __forceinline__ fx2 hi2(fx4 v) { return __builtin_shufflevector(v, v, 2, 3); }
__device__ __forceinline__ fx2 splat2(float x) { fx2 r; r.x = x; r.y = x; return r; }
__device__ __forceinline__ fx2 fma2(fx2 a, fx2 b, fx2 c) { return __builtin_elementwise_fma(a, b, c); }
__device__ __forceinline__ fx2 max2(fx2 a, fx2 b) { return __builtin_elementwise_max(a, b); }
__device__ __forceinline__ fx2 min2(fx2 a, fx2 b) { return __builtin_elementwise_min(a, b); }
__device__ __forceinline__ fx4 cat4(fx2 a, fx2 b) { return __builtin_shufflevector(a, b, 0, 1, 2, 3); }

// ---------------- K0: prep weights / paired codebook / zero loss+counter ----------------
__global__ __launch_bounds__(256) void k0_prep(
    const float* __restrict__ v_in, const float* __restrict__ g_in,
    const float* __restrict__ codebook, const float* __restrict__ v_out,
    const float* __restrict__ g_out, float* __restrict__ ws) {
    __shared__ float sred[5];
    int blk = blockIdx.x, tid = threadIdx.x;
    if (blk < 8) {
        int o = blk;
        const float* v = v_in + o * DIMN;
        float4 x = *(const float4*)(v + tid * 4);
        float p = x.x * x.x + x.y * x.y + x.z * x.z + x.w * x.w;
        for (int off = 32; off >= 1; off >>= 1) p += __shfl_down(p, off, 64);
        if ((tid & 63) == 0) sred[tid >> 6] = p;
        __syncthreads();
        if (tid == 0) {
            float tot = sred[0] + sred[1] + sred[2] + sred[3];
            sred[4] = g_in[o] / sqrtf(tot);
        }
        __syncthreads();
        float s = sred[4];
        ws[WS_WINT + (tid * 4 + 0) * 8 + o] = x.x * s;
        ws[WS_WINT + (tid * 4 + 1) * 8 + o] = x.y * s;
        ws[WS_WINT + (tid * 4 + 2) * 8 + o] = x.z * s;
        ws[WS_WINT + (tid * 4 + 3) * 8 + o] = x.w * s;
    } else if (blk < 12) {
        int r = (blk - 8) * 256 + tid;
        const float* v = v_out + r * 8;
        float4 a = *(const float4*)v;
        float4 b = *(const float4*)(v + 4);
        float n2 = dot4(a, a) + dot4(b, b);
        float s = g_out[r] / sqrtf(n2);
        *(float4*)(ws + WS_WOUT + r * 8)     = make_float4(a.x*s, a.y*s, a.z*s, a.w*s);
        *(float4*)(ws + WS_WOUT + r * 8 + 4) = make_float4(b.x*s, b.y*s, b.z*s, b.w*s);
    } else if (blk < 28) {
        int j = (blk - 12) * 256 + tid;
        const float* c = codebook + j * 8;
        float4 a = *(const float4*)c;
        float4 b = *(const float4*)(c + 4);
        float n2 = dot4(a, a) + dot4(b, b);
        float inv = 1.0f / fmaxf(sqrtf(n2), 1e-12f);
        float na[8] = {a.x*inv, a.y*inv, a.z*inv, a.w*inv,
                       b.x*inv, b.y*inv, b.z*inv, b.w*inv};
        // paired layout: pair j>>1, dim i, slot j&1
        float* dst = ws + WS_CNP + (size_t)(j >> 1) * 16 + (j & 1);
        #pragma unroll
        for (int i = 0; i < 8; i++) dst[i * 2] = na[i];
        float h = 0.0f;
        #pragma unroll
        for (int i = 0; i < 8; i++) h = fmaf(na[i], na[i], h);
        ws[WS_C2 + j] = -0.5f * h;                 // argmin dist == argmax dot+h
    } else {
        if (tid < 9) ws[WS_LOSS + tid] = 0.0f;     // 8 loss slots + counter
    }
}

// ---------------- K_ze: z -> z_e + e_n rows in ws ----------------
// grid 1024 = (b = blk>>7, 32-t tile = blk&127), 256 thr (8 p-chunks x 32 t), 8.7 KB LDS.
// Per-(t,c) chains bitwise-identical to proven k1a (ascending dd within p, ascending-p fold).
__global__ __launch_bounds__(256, 8) void k_ze(
    const float* __restrict__ z, const float* __restrict__ b_in,
    float* __restrict__ ws) {
    __shared__ float rows[32 * 68];
    int tid = threadIdx.x, blk = blockIdx.x;
    int b = blk >> 7;
    int t0 = (blk & 127) * 32;
    int p = tid >> 5, t = tid & 31;
    const float* zp = z + ((size_t)(b * DIMN + p * 128)) * TN + t0 + t;
    const float* wp = ws + WS_WINT + p * 128 * 8;   // wave-half-uniform -> dedup'd, L1-hot
    fx2 a0 = splat2(0.f), a1 = splat2(0.f), a2 = splat2(0.f), a3 = splat2(0.f);
    #pragma unroll 8
    for (int dd = 0; dd < 128; ++dd) {
        float zr = __builtin_nontemporal_load(zp + (size_t)dd * TN);
        fx4 w0 = *(const fx4*)(wp + dd * 8);
        fx4 w1 = *(const fx4*)(wp + dd * 8 + 4);
        fx2 zz = splat2(zr);
        a0 = fma2(lo2(w0), zz, a0);   // per-element IEEE fma == k1a scalar chain
        a1 = fma2(hi2(w0), zz, a1);
        a2 = fma2(lo2(w1), zz, a2);
        a3 = fma2(hi2(w1), zz, a3);
    }
    float* q = rows + t * 68 + p * 8;
    *(fx4*)(q)     = cat4(a0, a1);
    *(fx4*)(q + 4) = cat4(a2, a3);
    __syncthreads();
    if (tid < 32) {
        float4 za = *(const float4*)(b_in);
        float4 zb = *(const float4*)(b_in + 4);
        #pragma unroll
        for (int pp = 0; pp < 8; pp++) {           // ascending p: proven fold
            const float* r = rows + tid * 68 + pp * 8;
            add4(za, *(const float4*)(r));
            add4(zb, *(const float4*)(r + 4));
        }
        float inv = 1.0f / fmaxf(sqrtf(dot4(za, za) + dot4(zb, zb)), 1e-12f);
        float* o = ws + WS_ZEEN + ((size_t)(b * TN) + t0 + tid) * 16;
        *(float4*)(o)      = za;
        *(float4*)(o + 4)  = zb;
        *(float4*)(o + 8)  = make_float4(za.x*inv, za.y*inv, za.z*inv, za.w*inv);
        *(float4*)(o + 12) = make_float4(zb.x*inv, zb.y*inv, zb.z*inv, zb.w*inv);
    }
}

// ---------------- K_sc: search + merge + loss + idx + out-projection ----------------
// grid 1024 = (b = blk>>7, 32-t tile = blk&127), 256 thr, ~2 KB LDS -> 4 blocks/CU.
__global__ __launch_bounds__(256, 4) void k_sc(
    const float* __restrict__ codebook, const float* __restrict__ b_out,
    float* __restrict__ dout, float* __restrict__ ws) {
    __shared__ float cand[4 * 32 * 2];   // [wave][t][2]
    __shared__ float zq[8 * 32];         // z_q transposed [c][t]
    int tid = threadIdx.x, blk = blockIdx.x;
    int b = blk >> 7;
    int t0 = (blk & 127) * 32;
    int co = tid >> 3, tg = tid & 7;     // 32 code-octets x 8 t-groups x 4 t

    float en[4][8];
    #pragma unroll
    for (int k = 0; k < 4; k++) {
        const float* rp = ws + WS_ZEEN + ((size_t)(b * TN) + t0 + tg * 4 + k) * 16 + 8;
        fx4 u = *(const fx4*)rp;
        fx4 v = *(const fx4*)(rp + 4);
        en[k][0]=u.x; en[k][1]=u.y; en[k][2]=u.z; en[k][3]=u.w;
        en[k][4]=v.x; en[k][5]=v.y; en[k][6]=v.z; en[k][7]=v.w;
    }
    fx2 bs[4]; int bje[4], bjo[4];
    #pragma unroll
    for (int k = 0; k < 4; k++) { bs[k] = splat2(-3.4e38f); bje[k] = 0; bjo[k] = 1; }
    #pragma unroll 1
    for (int ci = 0; ci < 16; ++ci) {
        int j0 = ci * 256 + co * 8;                // my 8 codes = 4 pairs, ascending j
        const float* cg = ws + WS_CNP + (size_t)j0 * 8;
        #pragma unroll
        for (int pp = 0; pp < 4; ++pp) {
            fx4 cA = *(const fx4*)(cg + pp * 16);
            fx4 cB = *(const fx4*)(cg + pp * 16 + 4);
            fx4 cC = *(const fx4*)(cg + pp * 16 + 8);
            fx4 cD = *(const fx4*)(cg + pp * 16 + 12);
            fx2 h2 = *(const fx2*)(ws + WS_C2 + j0 + pp * 2);
            int jE = j0 + pp * 2;
            #pragma unroll
            for (int k = 0; k < 4; k++) {
                fx2 s = h2;                         // proven chain (round-4, passing)
                s = fma2(splat2(en[k][0]), lo2(cA), s);
                s = fma2(splat2(en[k][1]), hi2(cA), s);
                s = fma2(splat2(en[k][2]), lo2(cB), s);
                s = fma2(splat2(en[k][3]), hi2(cB), s);
                s = fma2(splat2(en[k][4]), lo2(cC), s);
                s = fma2(splat2(en[k][5]), hi2(cC), s);
                s = fma2(splat2(en[k][6]), lo2(cD), s);
                s = fma2(splat2(en[k][7]), hi2(cD), s);
                bool cE = s.x > bs[k].x;            // strict >: first-max per parity
                bool cO = s.y > bs[k].y;
                bs[k] = max2(bs[k], s);
                if (cE) bje[k] = jE;
                if (cO) bjo[k] = jE + 1;
            }
        }
    }
    // combine odd into even (global first-argmax: > or == && lower j)
    float bsF[4]; int bjF[4];
    #pragma unroll
    for (int k = 0; k < 4; k++) {
        bsF[k] = bs[k].x; bjF[k] = bje[k];
        if (bs[k].y > bsF[k] || (bs[k].y == bsF[k] && bjo[k] < bjF[k])) {
            bsF[k] = bs[k].y; bjF[k] = bjo[k];
        }
    }
    // in-wave butterfly across the 8 co's of this wave (lane bits 3,4,5)
    #pragma unroll
    for (int st = 8; st <= 32; st <<= 1) {
        #pragma unroll
        for (int k = 0; k < 4; k++) {
            float os = __shfl_xor(bsF[k], st, 64);
            int   oj = __shfl_xor(bjF[k], st, 64);
            if (os > bsF[k] || (os == bsF[k] && oj < bjF[k])) { bsF[k] = os; bjF[k] = oj; }
        }
    }
    if ((tid & 63) < 8) {                           // lane tg of each wave publishes
        int w = tid >> 6;
        #pragma unroll
        for (int k = 0; k < 4; k++)
            *(fx2*)(cand + (w * 32 + tg * 4 + k) * 2) =
                (fx2){bsF[k], __int_as_float(bjF[k])};
    }
    __syncthreads();

    // ---- merge 4 wave-cands + gather + zq + loss (tid<32) ----
    if (tid < 32) {
        int t = tid;
        fx2 c0 = *(const fx2*)(cand + t * 2);
        float best = c0.x; int idx = __float_as_int(c0.y);
        #pragma unroll
        for (int w2 = 1; w2 < 4; w2++) {
            fx2 cw = *(const fx2*)(cand + (w2 * 32 + t) * 2);
            int j2 = __float_as_int(cw.y);
            if (cw.x > best || (cw.x == best && j2 < idx)) { best = cw.x; idx = j2; }
        }
        dout[(size_t)OUT_ELEMS + b * TN + t0 + t] = (float)idx;
        const float* cq = codebook + (size_t)idx * 8;     // raw (un-normalized)
        float4 qa = *(const float4*)cq, qb = *(const float4*)(cq + 4);
        zq[0*32 + t] = qa.x; zq[1*32 + t] = qa.y;
        zq[2*32 + t] = qa.z; zq[3*32 + t] = qa.w;
        zq[4*32 + t] = qb.x; zq[5*32 + t] = qb.y;
        zq[6*32 + t] = qb.z; zq[7*32 + t] = qb.w;
        const float* zer = ws + WS_ZEEN + ((size_t)(b * TN) + t0 + t) * 16;
        float4 za = *(const float4*)(zer);
        float4 zb = *(const float4*)(zer + 4);
        float4 da = make_float4(za.x-qa.x, za.y-qa.y, za.z-qa.z, za.w-qa.w);
        float4 db = make_float4(zb.x-qb.x, zb.y-qb.y, zb.z-qb.z, zb.w-qb.w);
        float l = dot4(da, da) + dot4(db, db);
        for (int off = 16; off >= 1; off >>= 1) l += __shfl_down(l, off, 64);
        if (t == 0) atomicAdd(ws + WS_LOSS + b, l);
    }
    __syncthreads();

    // ---- out-projection: thread (t4 = tid&7, og = tid>>3) covers 4 t x 32 o ----
    {
        int t4 = tid & 7, og = tid >> 3;
        fx4 zr[8];
        #pragma unroll
        for (int c = 0; c < 8; c++) zr[c] = *(const fx4*)(zq + c * 32 + t4 * 4);
        fx2 cmn = splat2(-8.f), cmx = splat2(8.f);
        size_t obase = ((size_t)(b * DIMN + og * 32)) * TN + (size_t)(t0 + t4 * 4);
        for (int k = 0; k < 32; k++) {
            int o = og * 32 + k;
            const float* wr = ws + WS_WOUT + o * 8;   // L1-resident, dedup'd across lanes
            fx4 wa = *(const fx4*)(wr);
            fx4 wb = *(const fx4*)(wr + 4);
            float bo = b_out[o];
            fx2 accL = splat2(bo), accH = splat2(bo);
            float wcv[8] = {wa.x, wa.y, wa.z, wa.w, wb.x, wb.y, wb.z, wb.w};
            #pragma unroll
            for (int c = 0; c < 8; c++) {             // ascending c: proven chain
                fx2 ws2 = splat2(wcv[c]);
                accL = fma2(ws2, lo2(zr[c]), accL);
                accH = fma2(ws2, hi2(zr[c]), accH);
            }
            accL = min2(max2(accL, cmn), cmx);
            accH = min2(max2(accH, cmn), cmx);
            fx4 st = cat4(accL, accH);
            __builtin_nontemporal_store(st, (fx4*)(dout + obase + (size_t)k * TN));
        }
    }

    // ---- last block finalizes losses (device-scope counter pattern, proven) ----
    if (tid == 0) {
        __threadfence();
        unsigned int old = atomicAdd((unsigned int*)(ws + WS_CNT), 1u);
        if (old == 1023u) {
            #pragma unroll
            for (int i = 0; i < 8; i++) {
                float v = atomicAdd(ws + WS_LOSS + i, 0.0f);   // coherent read
                dout[(size_t)OUT_ELEMS + BTN + i] = v * (1.25f / 32768.0f);
            }
        }
    }
}

extern "C" void kernel_launch(void* const* d_in, const int* in_sizes, int n_in,
                              void* d_out, int out_size, void* d_ws, size_t ws_size,
                              hipStream_t stream) {
    (void)in_sizes; (void)n_in; (void)out_size; (void)ws_size;
    const float* z        = (const float*)d_in[0];
    const float* v_in     = (const float*)d_in[1];
    const float* g_in     = (const float*)d_in[2];
    const float* b_in     = (const float*)d_in[3];
    const float* codebook = (const float*)d_in[4];
    const float* v_out    = (const float*)d_in[5];
    const float* g_out    = (const float*)d_in[6];
    const float* b_out    = (const float*)d_in[7];
    float* out            = (float*)d_out;
    float* ws             = (float*)d_ws;

    hipLaunchKernelGGL(k0_prep, dim3(29), dim3(256), 0, stream,
                       v_in, g_in, codebook, v_out, g_out, ws);
    hipLaunchKernelGGL(k_ze, dim3(1024), dim3(256), 0, stream, z, b_in, ws);
    hipLaunchKernelGGL(k_sc, dim3(1024), dim3(256), 0, stream,
                       codebook, b_out, out, ws);
}

// Round 7
// 286.960 us; speedup vs baseline: 1.2139x; 1.2139x over previous
//
#include <hip/hip_runtime.h>

#define DIMN 1024
#define TN 4096
#define BN 8
#define CBN 4096
#define CDN 8
#define BTN (BN*TN)
#define OUT_ELEMS (BN*DIMN*TN)

typedef float fx4 __attribute__((ext_vector_type(4)));
typedef float fx2 __attribute__((ext_vector_type(2)));

// ws layout (float offsets)
#define WS_WINT 0          // W_in^T scaled: [d][8], 8192 floats
#define WS_WOUT 8192       // W_out scaled: [o][8], 8192 floats
#define WS_CN   16384      // normalized codebook [j][8], 32768 floats
#define WS_C2   49152      // h = -0.5*sum(c_n^2) per code, 4096 floats
#define WS_LOSS 86016      // 8 floats (per-batch loss accum)
#define WS_ZQ   131072     // z_q [b][c][t], 262144 floats (raw gathered codes)

// ---- k_mega LDS float offsets (round-3 proven layout, 62.8 KB -> 2 blocks/CU) ----
#define LZEP_F  9296       // zep partials: [64 t] stride 68, [8 p][8 c]
#define LZE_F   13648      // z_e [64][8]
#define LEN_F   14160      // e_n [64][8]
#define LCAND_F 14672      // candidates [4 waves][64 t][2]
#define LZQ_F   15184      // z_q transposed [8][64]
#define LDS_TOT 15696

__device__ __forceinline__ float dot4(float4 a, float4 b) {
    float d = a.x * b.x;
    d = fmaf(a.y, b.y, d);
    d = fmaf(a.z, b.z, d);
    d = fmaf(a.w, b.w, d);
    return d;
}
__device__ __forceinline__ void add4(float4& a, float4 b) {
    a.x += b.x; a.y += b.y; a.z += b.z; a.w += b.w;
}

// ---------------- K0: prep weights / codebook / zero loss (round-3 proven) ----------------
__global__ __launch_bounds__(256) void k0_prep(
    const float* __restrict__ v_in, const float* __restrict__ g_in,
    const float* __restrict__ codebook, const float* __restrict__ v_out,
    const float* __restrict__ g_out, float* __restrict__ ws) {
    __shared__ float sred[5];
    int blk = blockIdx.x, tid = threadIdx.x;
    if (blk < 8) {
        int o = blk;
        const float* v = v_in + o * DIMN;
        float4 x = *(const float4*)(v + tid * 4);
        float p = x.x * x.x + x.y * x.y + x.z * x.z + x.w * x.w;
        for (int off = 32; off >= 1; off >>= 1) p += __shfl_down(p, off, 64);
        if ((tid & 63) == 0) sred[tid >> 6] = p;
        __syncthreads();
        if (tid == 0) {
            float tot = sred[0] + sred[1] + sred[2] + sred[3];
            sred[4] = g_in[o] / sqrtf(tot);
        }
        __syncthreads();
        float s = sred[4];
        ws[WS_WINT + (tid * 4 + 0) * 8 + o] = x.x * s;
        ws[WS_WINT + (tid * 4 + 1) * 8 + o] = x.y * s;
        ws[WS_WINT + (tid * 4 + 2) * 8 + o] = x.z * s;
        ws[WS_WINT + (tid * 4 + 3) * 8 + o] = x.w * s;
    } else if (blk < 12) {
        int r = (blk - 8) * 256 + tid;
        const float* v = v_out + r * 8;
        float4 a = *(const float4*)v;
        float4 b = *(const float4*)(v + 4);
        float n2 = dot4(a, a) + dot4(b, b);
        float s = g_out[r] / sqrtf(n2);
        *(float4*)(ws + WS_WOUT + r * 8)     = make_float4(a.x*s, a.y*s, a.z*s, a.w*s);
        *(float4*)(ws + WS_WOUT + r * 8 + 4) = make_float4(b.x*s, b.y*s, b.z*s, b.w*s);
    } else if (blk < 28) {
        int j = (blk - 12) * 256 + tid;
        const float* c = codebook + j * 8;
        float4 a = *(const float4*)c;
        float4 b = *(const float4*)(c + 4);
        float n2 = dot4(a, a) + dot4(b, b);
        float inv = 1.0f / fmaxf(sqrtf(n2), 1e-12f);
        float4 na = make_float4(a.x*inv, a.y*inv, a.z*inv, a.w*inv);
        float4 nb = make_float4(b.x*inv, b.y*inv, b.z*inv, b.w*inv);
        *(float4*)(ws + WS_CN + j * 8)     = na;
        *(float4*)(ws + WS_CN + j * 8 + 4) = nb;
        ws[WS_C2 + j] = -0.5f * (dot4(na, na) + dot4(nb, nb));  // argmin dist == argmax dot+h
    } else {
        if (tid < 8) ws[WS_LOSS + tid] = 0.0f;
    }
}

// ---------------- K_mega2: z_e + search + merge + loss + idx + zq dump ----------------
// Round-3 k_mega verbatim through merge/gather/loss; out-projection removed; zq -> ws.
// grid 512 = (b = blk>>6, 64-t tile = blk&63), 256 threads, 62.8 KB LDS -> 2 blocks/CU.
__global__ __launch_bounds__(256, 2) void k_mega2(
    const float* __restrict__ z, const float* __restrict__ b_in,
    const float* __restrict__ codebook, float* __restrict__ dout,
    float* __restrict__ ws) {
    __shared__ float sp[LDS_TOT];
    int tid = threadIdx.x, blk = blockIdx.x;
    int b = blk >> 6;
    int t0 = (blk & 63) * 64;

    // ---- phase Z: stage W_in^T [1024][8] into region [0,8192) ----
    #pragma unroll
    for (int i = 0; i < 8; i++) {
        int f4 = tid + i * 256;
        *(float4*)(sp + f4 * 4) = *(const float4*)(ws + WS_WINT + f4 * 4);
    }
    __syncthreads();
    {
        // thread = (p-chunk = tid>>5, t-pair = tid&31); k1a-identical chains
        int p = tid >> 5, tpair = tid & 31;
        int tA = tpair * 2;
        const float* zp = z + ((size_t)(b * DIMN + p * 128)) * TN + t0 + tA;
        float4 a0a = make_float4(0.f,0.f,0.f,0.f), a0b = make_float4(0.f,0.f,0.f,0.f);
        float4 a1a = make_float4(0.f,0.f,0.f,0.f), a1b = make_float4(0.f,0.f,0.f,0.f);
        #pragma unroll 8
        for (int dd = 0; dd < 128; ++dd) {
            fx2 zv = __builtin_nontemporal_load((const fx2*)(zp + (size_t)dd * TN));
            const float* wv = sp + (p * 128 + dd) * 8;   // 32-lane-uniform -> broadcast
            float4 w0 = *(const float4*)wv;
            float4 w1 = *(const float4*)(wv + 4);
            a0a.x = fmaf(w0.x, zv.x, a0a.x); a0a.y = fmaf(w0.y, zv.x, a0a.y);
            a0a.z = fmaf(w0.z, zv.x, a0a.z); a0a.w = fmaf(w0.w, zv.x, a0a.w);
            a0b.x = fmaf(w1.x, zv.x, a0b.x); a0b.y = fmaf(w1.y, zv.x, a0b.y);
            a0b.z = fmaf(w1.z, zv.x, a0b.z); a0b.w = fmaf(w1.w, zv.x, a0b.w);
            a1a.x = fmaf(w0.x, zv.y, a1a.x); a1a.y = fmaf(w0.y, zv.y, a1a.y);
            a1a.z = fmaf(w0.z, zv.y, a1a.z); a1a.w = fmaf(w0.w, zv.y, a1a.w);
            a1b.x = fmaf(w1.x, zv.y, a1b.x); a1b.y = fmaf(w1.y, zv.y, a1b.y);
            a1b.z = fmaf(w1.z, zv.y, a1b.z); a1b.w = fmaf(w1.w, zv.y, a1b.w);
        }
        float* q0 = sp + LZEP_F + tA * 68 + p * 8;        // +4/t skew: spreads banks
        *(float4*)(q0)     = a0a;
        *(float4*)(q0 + 4) = a0b;
        float* q1 = sp + LZEP_F + (tA + 1) * 68 + p * 8;
        *(float4*)(q1)     = a1a;
        *(float4*)(q1 + 4) = a1b;
    }
    __syncthreads();

    // ---- fold + normalize (tid<64): bitwise-identical ascending-p fold ----
    if (tid < 64) {
        int t = tid;
        float4 za = *(const float4*)(b_in);
        float4 zb = *(const float4*)(b_in + 4);
        #pragma unroll
        for (int p = 0; p < 8; p++) {
            const float* pp = sp + LZEP_F + t * 68 + p * 8;
            add4(za, *(const float4*)(pp));
            add4(zb, *(const float4*)(pp + 4));
        }
        *(float4*)(sp + LZE_F + t * 8)     = za;
        *(float4*)(sp + LZE_F + t * 8 + 4) = zb;
        float inv = 1.0f / fmaxf(sqrtf(dot4(za, za) + dot4(zb, zb)), 1e-12f);
        *(float4*)(sp + LEN_F + t * 8)     = make_float4(za.x*inv, za.y*inv, za.z*inv, za.w*inv);
        *(float4*)(sp + LEN_F + t * 8 + 4) = make_float4(zb.x*inv, zb.y*inv, zb.z*inv, zb.w*inv);
    }
    __syncthreads();

    // ---- search: register-blocked, codes from L2, no LDS / no barriers in loop ----
    int co = tid >> 3, tt = tid & 7;   // 32 code-octets x 8 t-groups
    float en[8][8];                    // e_n for my 8 t's (static indexing only)
    #pragma unroll
    for (int k = 0; k < 8; k++) {
        float4 u = *(const float4*)(sp + LEN_F + (tt * 8 + k) * 8);
        float4 v = *(const float4*)(sp + LEN_F + (tt * 8 + k) * 8 + 4);
        en[k][0]=u.x; en[k][1]=u.y; en[k][2]=u.z; en[k][3]=u.w;
        en[k][4]=v.x; en[k][5]=v.y; en[k][6]=v.z; en[k][7]=v.w;
    }
    float bs[8]; int bj[8];
    #pragma unroll
    for (int k = 0; k < 8; k++) { bs[k] = -3.4e38f; bj[k] = 0; }
    #pragma unroll 1
    for (int ci = 0; ci < 16; ++ci) {
        int j0 = ci * 256 + co * 8;    // my 8 codes this chunk, ascending j across ci
        #pragma unroll
        for (int qh = 0; qh < 2; ++qh) {
            int jq = j0 + qh * 4;
            const float* cg = ws + WS_CN + (size_t)jq * 8;   // 128B contiguous / thread
            float4 ca[4], cb[4];
            #pragma unroll
            for (int k = 0; k < 4; k++) {
                ca[k] = *(const float4*)(cg + k * 8);
                cb[k] = *(const float4*)(cg + k * 8 + 4);
            }
            float4 hqv = *(const float4*)(ws + WS_C2 + jq);
            float hv[4] = {hqv.x, hqv.y, hqv.z, hqv.w};
            #pragma unroll
            for (int k = 0; k < 4; k++) {
                #pragma unroll
                for (int t = 0; t < 8; t++) {
                    float s = fmaf(en[t][0], ca[k].x, hv[k]);   // proven chain order
                    s = fmaf(en[t][1], ca[k].y, s); s = fmaf(en[t][2], ca[k].z, s);
                    s = fmaf(en[t][3], ca[k].w, s);
                    s = fmaf(en[t][4], cb[k].x, s); s = fmaf(en[t][5], cb[k].y, s);
                    s = fmaf(en[t][6], cb[k].z, s); s = fmaf(en[t][7], cb[k].w, s);
                    if (s > bs[t]) { bs[t] = s; bj[t] = jq + k; }  // strict >: lowest j
                }
            }
        }
    }
    // ---- in-wave merge across co (lowest-j-among-max is assoc+comm) ----
    #pragma unroll
    for (int st = 8; st <= 32; st <<= 1) {
        #pragma unroll
        for (int t = 0; t < 8; t++) {
            float os = __shfl_xor(bs[t], st, 64);
            int   oj = __shfl_xor(bj[t], st, 64);
            if (os > bs[t] || (os == bs[t] && oj < bj[t])) { bs[t] = os; bj[t] = oj; }
        }
    }
    if ((tid & 63) < 8) {              // lane tt of each wave publishes its 8 t's
        int w = tid >> 6;
        #pragma unroll
        for (int k = 0; k < 8; k++)
            *(float2*)(sp + LCAND_F + (w * 64 + tt * 8 + k) * 2) =
                make_float2(bs[k], __int_as_float(bj[k]));
    }
    __syncthreads();

    // ---- merge waves + gather + loss (tid<64) ----
    if (tid < 64) {
        int t = tid;
        float2 c0 = *(const float2*)(sp + LCAND_F + t * 2);
        float best = c0.x; int idx = __float_as_int(c0.y);
        #pragma unroll
        for (int w2 = 1; w2 < 4; w2++) {
            float2 cw = *(const float2*)(sp + LCAND_F + (w2 * 64 + t) * 2);
            int j2 = __float_as_int(cw.y);
            if (cw.x > best || (cw.x == best && j2 < idx)) { best = cw.x; idx = j2; }
        }
        dout[(size_t)OUT_ELEMS + b * TN + t0 + t] = (float)idx;
        const float* cq = codebook + (size_t)idx * 8;     // raw (un-normalized)
        float4 qa = *(const float4*)cq, qb = *(const float4*)(cq + 4);
        sp[LZQ_F + 0*64 + t] = qa.x; sp[LZQ_F + 1*64 + t] = qa.y;
        sp[LZQ_F + 2*64 + t] = qa.z; sp[LZQ_F + 3*64 + t] = qa.w;
        sp[LZQ_F + 4*64 + t] = qb.x; sp[LZQ_F + 5*64 + t] = qb.y;
        sp[LZQ_F + 6*64 + t] = qb.z; sp[LZQ_F + 7*64 + t] = qb.w;
        float4 za = *(const float4*)(sp + LZE_F + t * 8);
        float4 zb = *(const float4*)(sp + LZE_F + t * 8 + 4);
        float4 da = make_float4(za.x-qa.x, za.y-qa.y, za.z-qa.z, za.w-qa.w);
        float4 db = make_float4(zb.x-qb.x, zb.y-qb.y, zb.z-qb.z, zb.w-qb.w);
        float l = dot4(da, da) + dot4(db, db);
        for (int off = 32; off >= 1; off >>= 1) l += __shfl_down(l, off, 64);
        if (t == 0) atomicAdd(ws + WS_LOSS + b, l);
    }
    __syncthreads();

    // ---- dump z_q [8][64] -> ws zq[b][c][t0..t0+63] (exact float pass-through) ----
    #pragma unroll
    for (int i = 0; i < 2; i++) {
        int f = tid + i * 256;
        int c = f >> 6, t = f & 63;
        ws[WS_ZQ + ((size_t)(b * 8 + c)) * TN + t0 + t] = sp[LZQ_F + c * 64 + t];
    }
}

// ---------------- K_out: out = W_out @ z_q + b_out, contiguous 1KB bursts ----------------
// grid 512 = (b = blk>>6, o-chunk = (blk&63)>>1, t-half = blk&1), 256 thr, no LDS.
// Wave owns 8 o-rows; lanes cover 256 contiguous t per store -> 1KB nt bursts.
__global__ __launch_bounds__(256, 2) void k_out(
    const float* __restrict__ b_out, float* __restrict__ dout,
    const float* __restrict__ ws) {
    int tid = threadIdx.x, blk = blockIdx.x;
    int b = blk >> 6;
    int rem = blk & 63;
    int o0 = (rem >> 1) * 32;
    int tbase = (rem & 1) * 2048;
    int w = tid >> 6, lane = tid & 63;
    int ow0 = o0 + w * 8;

    // preload W rows + biases for my 8 o's (uniform per wave -> L1 broadcast)
    float wcv[8][8], bov[8];
    #pragma unroll
    for (int i = 0; i < 8; i++) {
        const float* wr = ws + WS_WOUT + (ow0 + i) * 8;
        float4 wa = *(const float4*)(wr);
        float4 wb = *(const float4*)(wr + 4);
        wcv[i][0]=wa.x; wcv[i][1]=wa.y; wcv[i][2]=wa.z; wcv[i][3]=wa.w;
        wcv[i][4]=wb.x; wcv[i][5]=wb.y; wcv[i][6]=wb.z; wcv[i][7]=wb.w;
        bov[i] = b_out[ow0 + i];
    }

    const float* zqb = ws + WS_ZQ + (size_t)(b * 8) * TN;
    #pragma unroll 1
    for (int tq = 0; tq < 8; ++tq) {
        int tt = tbase + tq * 256 + lane * 4;
        float4 zv[8];
        #pragma unroll
        for (int c = 0; c < 8; c++)
            zv[c] = *(const float4*)(zqb + (size_t)c * TN + tt);
        #pragma unroll
        for (int i = 0; i < 8; i++) {
            float bo = bov[i];
            float4 acc = make_float4(bo, bo, bo, bo);
            #pragma unroll
            for (int c = 0; c < 8; c++) {      // ascending c: proven epilogue chain
                float wc = wcv[i][c];
                acc.x = fmaf(wc, zv[c].x, acc.x);
                acc.y = fmaf(wc, zv[c].y, acc.y);
                acc.z = fmaf(wc, zv[c].z, acc.z);
                acc.w = fmaf(wc, zv[c].w, acc.w);
            }
            acc.x = fminf(fmaxf(acc.x, -8.f), 8.f);
            acc.y = fminf(fmaxf(acc.y, -8.f), 8.f);
            acc.z = fminf(fmaxf(acc.z, -8.f), 8.f);
            acc.w = fminf(fmaxf(acc.w, -8.f), 8.f);
            fx4 st; st.x = acc.x; st.y = acc.y; st.z = acc.z; st.w = acc.w;
            __builtin_nontemporal_store(st,
                (fx4*)(dout + ((size_t)(b * DIMN + ow0 + i)) * TN + tt));
        }
    }

    // loss finalize: k_mega2 finished (kernel order) -> values coherent
    if (blk == 0 && tid < 8) {
        dout[(size_t)OUT_ELEMS + BTN + tid] = ws[WS_LOSS + tid] * (1.25f / 32768.0f);
    }
}

extern "C" void kernel_launch(void* const* d_in, const int* in_sizes, int n_in,
                              void* d_out, int out_size, void* d_ws, size_t ws_size,
                              hipStream_t stream) {
    (void)in_sizes; (void)n_in; (void)out_size; (void)ws_size;
    const float* z        = (const float*)d_in[0];
    const float* v_in     = (const float*)d_in[1];
    const float* g_in     = (const float*)d_in[2];
    const float* b_in     = (const float*)d_in[3];
    const float* codebook = (const float*)d_in[4];
    const float* v_out    = (const float*)d_in[5];
    const float* g_out    = (const float*)d_in[6];
    const float* b_out    = (const float*)d_in[7];
    float* out            = (float*)d_out;
    float* ws             = (float*)d_ws;

    hipLaunchKernelGGL(k0_prep, dim3(29), dim3(256), 0, stream,
                       v_in, g_in, codebook, v_out, g_out, ws);
    hipLaunchKernelGGL(k_mega2, dim3(512), dim3(256), 0, stream,
                       z, b_in, codebook, out, ws);
    hipLaunchKernelGGL(k_out, dim3(512), dim3(256), 0, stream,
                       b_out, out, ws);
}